// Round 9
// baseline (768.799 us; speedup 1.0000x reference)
//
#include <hip/hip_runtime.h>
#include <math.h>

// SSIM via fully separable pipeline, software-pipelined staging, FUSED
// REDUCTION. img1,img2: [32,3,512,512] fp32 -> scalar mean.
//
// Round-11: the main loop is the round-3 kernel VERBATIM (proven clean:
// 84 VGPR, 181us, 84% VALUBusy, best of 8 rounds). The change is OUTSIDE
// the loop: every round showed a constant ~120-130us gap between
// ssim_kernel's dur and the benched total (R0:131, R1:125, R6:131, R7:120)
// -- second-dispatch overhead, not compute (the reduce kernel's work is
// ~5us). This version fuses the final reduction into ssim_kernel via the
// last-block-done pattern: partial write -> __threadfence -> atomicAdd on
// a counter; the block seeing old==nblocks-1 re-fences and reduces with
// the EXACT same strided order / double accumulation / shuffle tree as the
// old reduce_kernel (bit-identical result). Counter is hipMemsetAsync-
// zeroed pre-launch AND self-reset by the reducing block.
//
// SPILL BANS (8 rounds of evidence -- the loop body lives in a narrow
// codegen valley): __builtin_amdgcn_rcpf (3/3 spills), runtime row/ring
// indices, 4-plane LDS staging, 4-row-deep staging slots (R10: 16 live
// regs across the compute span -> 128-VGPR pin). Accumulator merges
// (hss/hsum, u/v) don't spill but are perf-neutral-to-negative (R4: 238us,
// R7: 216us): the kernel is NOT VALU-issue-count-bound. Busy-time floor
// ~152us; R1 wall 181us; all attempts at the residual 16% failed.
//
// Kept (T14, verified 272->181us): loads for rows r+2,r+3 ISSUED into
// registers right after the barrier, 2 rows of conv math run, then
// registers are COMMITTED to LDS. 2 rows/barrier, 4-row LDS ring.
// ring phase r%11 compile-time (pair period 22 == 0 mod 11).
//
// Round-2 lesson: __launch_bounds__(256,4) (128-VGPR cap) forced the ring
// into scratch. Cap at 256 VGPRs instead.

#define IH 512
#define IW 512
#define NCH 96            // 32*3 depthwise channels
#define TW 256            // tile width == blockDim.x
#define TH 34             // output rows per block
#define SSTR 272          // LDS row stride (266 used)
#define TYB 16            // ceil(512/34) block-rows
#define NBLK (NCH * TYB * 2)   // 3072
#define C1f (0.01f * 0.01f)
#define C2f (0.03f * 0.03f)

struct Weights { float w[11]; };

__global__ __launch_bounds__(256, 2) void ssim_kernel(
    const float* __restrict__ img1, const float* __restrict__ img2,
    float* __restrict__ partial, unsigned* __restrict__ ctr,
    float* __restrict__ out, double inv_count, Weights wt)
{
    __shared__ float sA[2][SSTR];
    __shared__ float sB[2][SSTR];
    __shared__ float wave_sums[4];

    const int tid = threadIdx.x;
    const int bx  = blockIdx.x;
    const int tx  = bx & 1;          // 2 col tiles
    const int ty  = (bx >> 1) & 15;  // 16 row tiles
    const int ch  = bx >> 5;         // 96 channels

    const int col0     = tx * TW;
    const int row_out0 = ty * TH;
    const int row0     = row_out0 - 5;       // staging row r -> global row row0+r
    const size_t choff = (size_t)ch * IH * IW;

    // column halo indices (fixed per thread)
    const int  gc0   = col0 - 5 + tid;
    const bool colv0 = ((unsigned)gc0 < (unsigned)IW);
    const int  gc1   = gc0 + TW;                   // staged by tid < 10
    const bool colv1 = ((unsigned)gc1 < (unsigned)IW);
    const bool halo  = (tid < 10);

    // two register staging slots (fixed names -> no runtime reg indexing)
    float pa0, pb0, pa1, pb1;        // slot P: even row of the pair
    float qa0, qb0, qa1, qb1;        // slot Q: odd row of the pair

    auto issue = [&](int r, float& a0, float& b0, float& a1, float& b1) {
        const int gr = row0 + r;                   // wave-uniform
        const bool rowv = ((unsigned)gr < (unsigned)IH);
        const long rowoff = (long)choff + (long)gr * IW;
        a0 = 0.f; b0 = 0.f; a1 = 0.f; b1 = 0.f;
        if (rowv & colv0) {
            a0 = img1[rowoff + gc0];
            b0 = img2[rowoff + gc0];
        }
        if (rowv & colv1 & halo) {
            a1 = img1[rowoff + gc1];
            b1 = img2[rowoff + gc1];
        }
    };
    auto commit = [&](int r, float a0, float b0, float a1, float b1) {
        const int p = (r & 1);
        sA[p][tid] = a0;
        sB[p][tid] = b0;
        if (halo) {
            sA[p][tid + TW] = a1;
            sB[p][tid + TW] = b1;
        }
    };

    // accumulator ring: slot s holds output row o with o % 11 == s.
    // Zero-init only to avoid reading junk in the (discarded) warm-up emits.
    float acc0[11], acc1[11], acc2[11], acc3[11], acc4[11];
    #pragma unroll
    for (int s = 0; s < 11; ++s)
        acc0[s] = acc1[s] = acc2[s] = acc3[s] = acc4[s] = 0.f;

    float tsum = 0.f;

    // prologue: rows 0,1 staged (one-time full-latency wait)
    issue(0, pa0, pb0, pa1, pb1);
    issue(1, qa0, qb0, qa1, qb1);
    commit(0, pa0, pb0, pa1, pb1);
    commit(1, qa0, qb0, qa1, qb1);

    for (int g = 0; g < 2; ++g) {
        #pragma unroll
        for (int jj = 0; jj < 11; ++jj) {
            const int rp = g * 22 + jj * 2;   // this pair computes rows rp, rp+1
            __syncthreads();                  // prev commits visible; prev reads done

            const bool more = (rp + 2) < 44;  // wave-uniform
            if (more) {
                issue(rp + 2, pa0, pb0, pa1, pb1);
                issue(rp + 3, qa0, qb0, qa1, qb1);
            }

            #pragma unroll
            for (int e = 0; e < 2; ++e) {
                const int r  = rp + e;
                const int ph = (2 * jj + e) % 11;   // == r % 11, compile-time
                const int p  = r & 1;               // LDS buffer parity

                // ---- horizontal 11-tap conv straight from LDS ----
                const float* __restrict__ rowA = &sA[p][tid];
                const float* __restrict__ rowB = &sB[p][tid];
                float hx = 0.f, hy = 0.f, hxx = 0.f, hyy = 0.f, hxy = 0.f;
                #pragma unroll
                for (int k = 0; k < 11; ++k) {
                    const float a  = rowA[k];
                    const float b  = rowB[k];
                    const float wk = wt.w[k];
                    const float ta = wk * a;
                    const float tb = wk * b;
                    hx  += ta;
                    hy  += tb;
                    hxx += ta * a;
                    hyy += tb * b;
                    hxy += ta * b;
                }

                // ---- vertical conv: scatter into ring, weight idx (ph-s) mod 11.
                //      wi==0 is the first tap of the slot's window -> assign. ----
                #pragma unroll
                for (int s = 0; s < 11; ++s) {
                    const int wi = (ph - s + 11) % 11;   // compile-time
                    const float wk = wt.w[wi];
                    if (wi == 0) {
                        acc0[s] = wk * hx;
                        acc1[s] = wk * hy;
                        acc2[s] = wk * hxx;
                        acc3[s] = wk * hyy;
                        acc4[s] = wk * hxy;
                    } else {
                        acc0[s] += wk * hx;
                        acc1[s] += wk * hy;
                        acc2[s] += wk * hxx;
                        acc3[s] += wk * hyy;
                        acc4[s] += wk * hxy;
                    }
                }

                // ---- emit output row o = r-10 (slot (ph+1)%11) ----
                const int se = (ph + 1) % 11;           // compile-time
                const float mu1 = acc0[se], mu2 = acc1[se];
                const float m11 = acc2[se], m22 = acc3[se], m12 = acc4[se];

                const float mu1s = mu1 * mu1;
                const float mu2s = mu2 * mu2;
                const float mu12 = mu1 * mu2;
                const float num = (2.f * mu12 + C1f) * (2.f * (m12 - mu12) + C2f);
                const float den = (mu1s + mu2s + C1f) *
                                  ((m11 - mu1s) + (m22 - mu2s) + C2f);
                const int o = r - 10;
                const bool valid = (o >= 0) && (row_out0 + o < IH);
                tsum += valid ? (num / den) : 0.f;
            }

            // ---- commit the prefetched pair: vmcnt wait covered by the
            //      conv math above. Loads never cross the barrier. ----
            if (more) {
                commit(rp + 2, pa0, pb0, pa1, pb1);
                commit(rp + 3, qa0, qb0, qa1, qb1);
            }
        }
    }

    // ---- block reduction ----
    #pragma unroll
    for (int off = 32; off > 0; off >>= 1)
        tsum += __shfl_down(tsum, off);
    if ((tid & 63) == 0) wave_sums[tid >> 6] = tsum;
    __syncthreads();
    if (tid == 0) {
        partial[bx] =
            wave_sums[0] + wave_sums[1] + wave_sums[2] + wave_sums[3];
    }

    // ---- fused final reduction: last-block-done pattern ----
    __shared__ unsigned is_last;
    __threadfence();                         // partial[bx] visible device-wide
    if (tid == 0) {
        const unsigned old = atomicAdd(ctr, 1u);
        is_last = (old == (unsigned)(NBLK - 1)) ? 1u : 0u;
    }
    __syncthreads();
    if (is_last) {
        __threadfence();                     // acquire all partials
        __shared__ double dsum[4];
        double s = 0.0;
        for (int i = tid; i < NBLK; i += 256) s += (double)partial[i];
        #pragma unroll
        for (int off = 32; off > 0; off >>= 1)
            s += __shfl_down(s, off);
        if ((tid & 63) == 0) dsum[tid >> 6] = s;
        __syncthreads();
        if (tid == 0) {
            out[0] = (float)((dsum[0] + dsum[1] + dsum[2] + dsum[3]) *
                             inv_count);
            atomicExch(ctr, 0u);             // self-reset for next replay
        }
    }
}

extern "C" void kernel_launch(void* const* d_in, const int* in_sizes, int n_in,
                              void* d_out, int out_size, void* d_ws, size_t ws_size,
                              hipStream_t stream)
{
    const float* img1 = (const float*)d_in[0];
    const float* img2 = (const float*)d_in[1];
    float* out = (float*)d_out;
    float* partial = (float*)d_ws;                 // 3072 floats
    unsigned* ctr = (unsigned*)(partial + NBLK);   // +4 bytes

    // Gaussian window (ws=11, sigma=1.5) in fp32, matching the reference
    Weights wt;
    {
        float s = 0.f;
        for (int i = 0; i < 11; ++i) {
            const float d = (float)(i - 5);
            wt.w[i] = expf(-(d * d) / 4.5f);
            s += wt.w[i];
        }
        for (int i = 0; i < 11; ++i) wt.w[i] /= s;
    }

    // zero the done-counter (graph-capturable async memset; the kernel also
    // self-resets it, this guards the very first run)
    hipMemsetAsync(ctr, 0, sizeof(unsigned), stream);

    const double inv_count = 1.0 / ((double)NCH * IH * IW);
    ssim_kernel<<<NBLK, 256, 0, stream>>>(img1, img2, partial, ctr, out,
                                          inv_count, wt);
}